// Round 11
// baseline (159.993 us; speedup 1.0000x reference)
//
#include <hip/hip_runtime.h>

typedef float f32x4  __attribute__((ext_vector_type(4)));
typedef float f32x16 __attribute__((ext_vector_type(16)));
typedef __bf16 bf16x8 __attribute__((ext_vector_type(8)));

#define SPAT 65536   // t*h*w
#define CH   128
#define NE   8

// LDS layout (bytes), total 150,144
#define XT_OFF    0        // 65536 : X tile bf16 [256][128], granule-XOR swizzle
#define OA_OFF    65536    // 69904 : out-acc bf16, 257 rows x 272B row stride
#define OA_ROWB   272
#define B1_OFF    135440   // 4096  : b1 f32[8][128]
#define B2_OFF    139536   // 4096  : b2 f32[8][128]
#define SLT_OFF   143632   // 2048  : slotTok u16[1024]
#define SLC_OFF   145680   // 4096  : slotCe  f32[1024]
#define DSC_OFF   149776   // 128   : group descs u32[32] (e<<16 | slotBase)
#define CNT_OFF   149904   // 192   : u32[48]: cntP8,cntQ8,curP8,curQ8,baseP8,baseQ8
#define AL_OFF    150096   // 32    : alpha f32[8]
#define NG_OFF    150128   // 16    : NGP, NGtot
#define LDS_BYTES 150144

static __device__ __forceinline__ unsigned short bf(float f) {
    __bf16 h = (__bf16)f; return __builtin_bit_cast(unsigned short, h);
}
static __device__ __forceinline__ unsigned pk2(float a, float b) {
    return (unsigned)bf(a) | ((unsigned)bf(b) << 16);
}
static __device__ __forceinline__ float ub(unsigned short u) {
    return __builtin_bit_cast(float, (unsigned)u << 16);
}

// Pre-convert W1/W2 fp32 -> bf16 images, NATURAL granule order. W1 rows keep
// the R7/R8-verified PERMUTATION so GEMM1's D-fragment == GEMM2's B-fragment:
//   image row r holds real W1 row P(r): n = 4*(r>>5) + ((r>>3)&3),
//   P(r) = (n>>1)*16 + ((r>>2)&1)*8 + (n&1)*4 + (r&3). W2 rows natural.
__global__ void conv_w(const float* __restrict__ W1, const float* __restrict__ W2,
                       unsigned char* __restrict__ wimg) {
    const int gid = blockIdx.x * 256 + threadIdx.x;   // 32768 granules
    const int mat = gid >> 14;
    const int e   = (gid >> 11) & 7;
    const int r   = (gid >> 4) & 127;
    const int p   = gid & 15;
    int src_row = r;
    if (mat == 0) {
        const int n = 4 * (r >> 5) + ((r >> 3) & 3);
        src_row = (n >> 1) * 16 + ((r >> 2) & 1) * 8 + (n & 1) * 4 + (r & 3);
    }
    const float* s = (mat ? W2 : W1) + (e * 16384 + src_row * 128 + p * 8);
    uint4 pk;
    pk.x = pk2(s[0], s[1]); pk.y = pk2(s[2], s[3]);
    pk.z = pk2(s[4], s[5]); pk.w = pk2(s[6], s[7]);
    *(uint4*)(wimg + mat * 262144 + e * 32768 + r * 256 + p * 16) = pk;
}

// One compacted group of 32 slots (one expert). W1-pass builds the FULL pa[8]
// (h1 in registers), then W2-pass accumulates D. Both passes fully unrolled so
// the compiler hoists L2 weight loads ahead of the MFMAs (R10's unroll-1 made
// every load latency-exposed: 7% MFMA / 19% VALU / rest stall).
template<bool ADD>
static __device__ __forceinline__ void group_body(
        unsigned char* smem, const unsigned char* __restrict__ wimg,
        int g, int l31, int hi)
{
    const unsigned desc = ((const unsigned*)(smem + DSC_OFF))[g];
    const int e  = (int)(desc >> 16);
    const int s  = (int)(desc & 0xFFFFu) + l31;
    const unsigned tokRaw = ((const unsigned short*)(smem + SLT_OFF))[s];
    const float ce = ((const float*)(smem + SLC_OFF))[s];
    const int tokx  = (int)(tokRaw & 255u);
    const int rowOA = (tokRaw > 255u) ? 256 : (int)tokRaw;
    const float alph = ((const float*)(smem + AL_OFF))[e];

    // gather this slot's x fragments from XT
    uint4 xb[8];
    #pragma unroll
    for (int kc = 0; kc < 8; ++kc)
        xb[kc] = *(const uint4*)(smem + XT_OFF + tokx * 256
                                  + (((2 * kc + hi) ^ (tokx & 15)) * 16));

    const unsigned char* W1i = wimg + e * 32768;
    const unsigned char* W2i = wimg + 262144 + e * 32768;

    // ---- W1 pass: full pa[8] (32KB W1 image streamed once) ----
    uint4 pa[8];
    #pragma unroll
    for (int gt = 0; gt < 4; ++gt) {
        uint4 a1[8];
        #pragma unroll
        for (int kc = 0; kc < 8; ++kc)
            a1[kc] = *(const uint4*)(W1i + (gt * 32 + l31) * 256 + (2 * kc + hi) * 16);
        f32x16 h0 = {}, h1 = {};
        #pragma unroll
        for (int kc = 0; kc < 4; ++kc) {
            h0 = __builtin_amdgcn_mfma_f32_32x32x16_bf16(
                    __builtin_bit_cast(bf16x8, a1[2 * kc]),
                    __builtin_bit_cast(bf16x8, xb[2 * kc]), h0, 0, 0, 0);
            h1 = __builtin_amdgcn_mfma_f32_32x32x16_bf16(
                    __builtin_bit_cast(bf16x8, a1[2 * kc + 1]),
                    __builtin_bit_cast(bf16x8, xb[2 * kc + 1]), h1, 0, 0, 0);
        }
        #pragma unroll
        for (int q = 0; q < 4; ++q) {
            const int kt2 = 2 * gt + (q >> 1), half = q & 1;
            const int obase = kt2 * 16 + hi * 8 + half * 4;
            const f32x4 b1v = *(const f32x4*)(smem + B1_OFF + e * 512 + obase * 4);
            float hv[4];
            #pragma unroll
            for (int i = 0; i < 4; ++i) {
                float z = h0[q * 4 + i] + h1[q * 4 + i] + b1v[i];
                z = fmaxf(z, 0.f) + alph * fminf(z, 0.f);
                hv[i] = z * ce;
            }
            ((unsigned*)&pa[kt2])[half * 2]     = pk2(hv[0], hv[1]);
            ((unsigned*)&pa[kt2])[half * 2 + 1] = pk2(hv[2], hv[3]);
        }
    }

    // ---- W2 pass: D accumulate (32KB W2 image streamed once) ----
    f32x16 D[4] = {};   // D[n2]: rows p = n2*32+8q+4hi+i, col = this slot's token
    #pragma unroll
    for (int kt2 = 0; kt2 < 8; ++kt2) {
        uint4 wf[4];
        #pragma unroll
        for (int n2 = 0; n2 < 4; ++n2)
            wf[n2] = *(const uint4*)(W2i + (n2 * 32 + l31) * 256 + (2 * kt2 + hi) * 16);
        #pragma unroll
        for (int n2 = 0; n2 < 4; ++n2)
            D[n2] = __builtin_amdgcn_mfma_f32_32x32x16_bf16(
                    __builtin_bit_cast(bf16x8, wf[n2]),
                    __builtin_bit_cast(bf16x8, pa[kt2]), D[n2], 0, 0, 0);
    }

    // + ce*b2, commit to OA (P0: write; P1: read-add-write)
    unsigned char* oarow = smem + OA_OFF + rowOA * OA_ROWB;
    #pragma unroll
    for (int n2 = 0; n2 < 4; ++n2) {
        #pragma unroll
        for (int q = 0; q < 4; ++q) {
            const int p0 = n2 * 32 + q * 8 + hi * 4;
            const f32x4 b2v = *(const f32x4*)(smem + B2_OFF + e * 512 + p0 * 4);
            float vv[4];
            #pragma unroll
            for (int i = 0; i < 4; ++i) vv[i] = D[n2][q * 4 + i] + ce * b2v[i];
            uint2* dst = (uint2*)(oarow + p0 * 2);
            if (ADD) {
                const uint2 old = *dst;
                vv[0] += ub((unsigned short)(old.x & 0xFFFFu));
                vv[1] += ub((unsigned short)(old.x >> 16));
                vv[2] += ub((unsigned short)(old.y & 0xFFFFu));
                vv[3] += ub((unsigned short)(old.y >> 16));
            }
            uint2 nw; nw.x = pk2(vv[0], vv[1]); nw.y = pk2(vv[2], vv[3]);
            *dst = nw;
        }
    }
}

__global__ __launch_bounds__(512) __attribute__((amdgpu_waves_per_eu(2, 2)))
void moe_main(const float* __restrict__ x,  const float* __restrict__ gw,
              const float* __restrict__ gb, const float* __restrict__ b1,
              const float* __restrict__ alpha, const float* __restrict__ b2,
              const unsigned char* __restrict__ wimg, float* __restrict__ out)
{
    __shared__ __align__(16) unsigned char smem[LDS_BYTES];
    const int t = threadIdx.x, lane = t & 63, w = t >> 6, blk = blockIdx.x;
    const int l31 = lane & 31, hi = lane >> 5;
    const size_t xbase = (size_t)(blk >> 8) * (size_t)(CH * SPAT) + (size_t)((blk & 255) << 8);
    const int m = w * 32 + l31;           // owner token (hi duplicates)
    unsigned* C = (unsigned*)(smem + CNT_OFF);

    if (t < 48) C[t] = 0;
    if (t < 256)      ((f32x4*)(smem + B1_OFF))[t]       = ((const f32x4*)b1)[t];
    else              ((f32x4*)(smem + B2_OFF))[t - 256] = ((const f32x4*)b2)[t - 256];
    if (t < 8) ((float*)(smem + AL_OFF))[t] = alpha[t];

    // ---- x load -> XT (bf16, swizzled) + fp32 gating ----
    f32x4 plo = {0.f,0.f,0.f,0.f}, phi = {0.f,0.f,0.f,0.f};
    #pragma unroll
    for (int kc = 0; kc < 8; ++kc) {
        const int c0 = kc * 16 + hi * 8;
        float v8[8];
        #pragma unroll
        for (int j = 0; j < 8; ++j) v8[j] = x[xbase + (size_t)(c0 + j) * SPAT + m];
        #pragma unroll
        for (int j = 0; j < 8; ++j) {
            const f32x4 g0 = *(const f32x4*)(gw + (c0 + j) * NE);
            const f32x4 g1 = *(const f32x4*)(gw + (c0 + j) * NE + 4);
            plo += v8[j] * g0; phi += v8[j] * g1;
        }
        uint4 pkv;
        pkv.x = pk2(v8[0], v8[1]); pkv.y = pk2(v8[2], v8[3]);
        pkv.z = pk2(v8[4], v8[5]); pkv.w = pk2(v8[6], v8[7]);
        *(uint4*)(smem + XT_OFF + m * 256 + (((2 * kc + hi) ^ (m & 15)) * 16)) = pkv;
    }
    #pragma unroll
    for (int i2 = 0; i2 < 4; ++i2) {
        plo[i2] += __shfl_xor(plo[i2], 32, 64);
        phi[i2] += __shfl_xor(phi[i2], 32, 64);
    }
    int i0, i1; float q0, q1;
    {
        float lg[8];
        #pragma unroll
        for (int e2 = 0; e2 < 4; ++e2) { lg[e2] = plo[e2] + gb[e2]; lg[4 + e2] = phi[e2] + gb[4 + e2]; }
        i0 = 0; float v0 = lg[0];
        #pragma unroll
        for (int e2 = 1; e2 < 8; ++e2) if (lg[e2] > v0) { v0 = lg[e2]; i0 = e2; }
        i1 = -1; float v1 = -3.4e38f;
        #pragma unroll
        for (int e2 = 0; e2 < 8; ++e2) if (e2 != i0 && lg[e2] > v1) { v1 = lg[e2]; i1 = e2; }
        const float d = expf(v1 - v0);
        q0 = 1.f / (1.f + d);
        q1 = d   / (1.f + d);
    }
    __syncthreads();   // S1: counters zeroed, XT/params done

    if (hi == 0) {
        atomicAdd(&C[i0], 1u);
        atomicAdd(&C[8 + i1], 1u);
    }
    __syncthreads();   // S2

    if (t == 0) {      // build bases, cursors, group descriptors (expert-sorted)
        unsigned* dsc = (unsigned*)(smem + DSC_OFF);
        int ng = 0; unsigned base = 0;
        for (int e = 0; e < 8; ++e) {
            const unsigned c = C[e], gc = (c + 31) >> 5;
            C[16 + e] = base; C[32 + e] = base;
            for (unsigned k = 0; k < gc; ++k) dsc[ng++] = ((unsigned)e << 16) | (base + k * 32);
            base += gc * 32;
        }
        ((int*)(smem + NG_OFF))[0] = ng;
        for (int e = 0; e < 8; ++e) {
            const unsigned c = C[8 + e], gc = (c + 31) >> 5;
            C[24 + e] = base; C[40 + e] = base;
            for (unsigned k = 0; k < gc; ++k) dsc[ng++] = ((unsigned)e << 16) | (base + k * 32);
            base += gc * 32;
        }
        ((int*)(smem + NG_OFF))[1] = ng;
    }
    __syncthreads();   // S3

    if (hi == 0) {     // scatter
        const unsigned pP = atomicAdd(&C[16 + i0], 1u);
        ((unsigned short*)(smem + SLT_OFF))[pP] = (unsigned short)m;
        ((float*)(smem + SLC_OFF))[pP] = q0;
        const unsigned pQ = atomicAdd(&C[24 + i1], 1u);
        ((unsigned short*)(smem + SLT_OFF))[pQ] = (unsigned short)m;
        ((float*)(smem + SLC_OFF))[pQ] = q1;
    }
    __syncthreads();   // S4

    if (t < 16) {      // pad each expert segment to x32 with dummy slots
        const int e = t & 7;
        const unsigned c  = (t < 8) ? C[e] : C[8 + e];
        const unsigned bs = (t < 8) ? C[32 + e] : C[40 + e];
        const unsigned en = bs + ((c + 31) & ~31u);
        for (unsigned s2 = bs + c; s2 < en; ++s2) {
            ((unsigned short*)(smem + SLT_OFF))[s2] = 0xFFFFu;
            ((float*)(smem + SLC_OFF))[s2] = 0.f;
        }
    }
    __syncthreads();   // S5

    const int NGP = ((const int*)(smem + NG_OFF))[0];
    const int NGT = ((const int*)(smem + NG_OFF))[1];

    // contiguous (expert-adjacent) wave->group ranges for L1/L2 weight locality
    // Phase P0: primary slots (every token exactly once) -> WRITE OA
    {
        const int g0 = (w * NGP) >> 3, g1 = ((w + 1) * NGP) >> 3;
        #pragma unroll 1
        for (int g = g0; g < g1; ++g) group_body<false>(smem, wimg, g, l31, hi);
    }
    __syncthreads();   // S6: OA fully initialized
    // Phase P1: secondary slots -> read-add-write OA
    {
        const int ns = NGT - NGP;
        const int g0 = NGP + ((w * ns) >> 3), g1 = NGP + (((w + 1) * ns) >> 3);
        #pragma unroll 1
        for (int g = g0; g < g1; ++g) group_body<true>(smem, wimg, g, l31, hi);
    }
    __syncthreads();   // S7

    // ---- epilogue: out[p][tok] = OA[tok][p] + x[p][tok] ----
    {
        const int etok = t & 255;
        const int gb8  = (t >> 8) * 8;
        const unsigned char* oarow = smem + OA_OFF + etok * OA_ROWB;
        #pragma unroll
        for (int gi = 0; gi < 8; ++gi) {
            const int gran = gb8 + gi;
            const uint4 r = *(const uint4*)(oarow + gran * 16);
            const unsigned short* u = (const unsigned short*)&r;
            #pragma unroll
            for (int j = 0; j < 8; ++j) {
                const int p = gran * 8 + j;
                const size_t a = xbase + (size_t)p * SPAT + etok;
                out[a] = ub(u[j]) + x[a];
            }
        }
    }
}

extern "C" void kernel_launch(void* const* d_in, const int* in_sizes, int n_in,
                              void* d_out, int out_size, void* d_ws, size_t ws_size,
                              hipStream_t stream) {
    const float* x  = (const float*)d_in[0];
    const float* gw = (const float*)d_in[1];
    const float* gb = (const float*)d_in[2];
    const float* W1 = (const float*)d_in[3];
    const float* b1 = (const float*)d_in[4];
    const float* al = (const float*)d_in[5];
    const float* W2 = (const float*)d_in[6];
    const float* b2 = (const float*)d_in[7];
    (void)in_sizes; (void)n_in; (void)out_size; (void)ws_size;
    unsigned char* wimg = (unsigned char*)d_ws;   // needs 512 KiB
    float* out = (float*)d_out;

    conv_w<<<dim3(128), dim3(256), 0, stream>>>(W1, W2, wimg);
    moe_main<<<dim3(512), dim3(512), 0, stream>>>(x, gw, gb, b1, al, b2, wimg, out);
}

// Round 12
// 140.745 us; speedup vs baseline: 1.1368x; 1.1368x over previous
//
#include <hip/hip_runtime.h>

typedef float f32x4  __attribute__((ext_vector_type(4)));
typedef float f32x16 __attribute__((ext_vector_type(16)));
typedef __bf16 bf16x8 __attribute__((ext_vector_type(8)));

#define SPAT 65536   // t*h*w
#define CH   128
#define NE   8

// LDS layout (bytes), total 150,144
#define XT_OFF    0        // 65536 : X tile bf16 [256][128], granule-XOR swizzle
#define OA_OFF    65536    // 69904 : out-acc bf16, 257 rows x 272B row stride
#define OA_ROWB   272
#define B1_OFF    135440   // 4096  : b1 f32[8][128]
#define B2_OFF    139536   // 4096  : b2 f32[8][128]
#define SLT_OFF   143632   // 2048  : slotTok u16[1024]
#define SLC_OFF   145680   // 4096  : slotCe  f32[1024]
#define DSC_OFF   149776   // 128   : group descs u32[32] (e<<16 | slotBase)
#define CNT_OFF   149904   // 192   : u32[48]
#define AL_OFF    150096   // 32    : alpha f32[8]
#define NG_OFF    150128   // 16    : NGP, NGtot
#define LDS_BYTES 150144

#define SB() __builtin_amdgcn_sched_barrier(0)

static __device__ __forceinline__ unsigned short bf(float f) {
    __bf16 h = (__bf16)f; return __builtin_bit_cast(unsigned short, h);
}
static __device__ __forceinline__ unsigned pk2(float a, float b) {
    return (unsigned)bf(a) | ((unsigned)bf(b) << 16);
}
static __device__ __forceinline__ float ub(unsigned short u) {
    return __builtin_bit_cast(float, (unsigned)u << 16);
}

// Pre-convert W1/W2 fp32 -> bf16 images, NATURAL granule order. W1 rows keep
// the R7/R8-verified PERMUTATION so GEMM1's D-fragment == GEMM2's B-fragment:
//   image row r holds real W1 row P(r): n = 4*(r>>5) + ((r>>3)&3),
//   P(r) = (n>>1)*16 + ((r>>2)&1)*8 + (n&1)*4 + (r&3). W2 rows natural.
__global__ void conv_w(const float* __restrict__ W1, const float* __restrict__ W2,
                       unsigned char* __restrict__ wimg) {
    const int gid = blockIdx.x * 256 + threadIdx.x;   // 32768 granules
    const int mat = gid >> 14;
    const int e   = (gid >> 11) & 7;
    const int r   = (gid >> 4) & 127;
    const int p   = gid & 15;
    int src_row = r;
    if (mat == 0) {
        const int n = 4 * (r >> 5) + ((r >> 3) & 3);
        src_row = (n >> 1) * 16 + ((r >> 2) & 1) * 8 + (n & 1) * 4 + (r & 3);
    }
    const float* s = (mat ? W2 : W1) + (e * 16384 + src_row * 128 + p * 8);
    uint4 pk;
    pk.x = pk2(s[0], s[1]); pk.y = pk2(s[2], s[3]);
    pk.z = pk2(s[4], s[5]); pk.w = pk2(s[6], s[7]);
    *(uint4*)(wimg + mat * 262144 + e * 32768 + r * 256 + p * 16) = pk;
}

// ---- pipeline stage helpers (all indices compile-time after inlining) ----
static __device__ __forceinline__ void ld_a1(uint4* buf, const unsigned char* __restrict__ W1i,
                                             int gt, int l31, int hi) {
    #pragma unroll
    for (int kc = 0; kc < 8; ++kc)
        buf[kc] = *(const uint4*)(W1i + (gt * 32 + l31) * 256 + (2 * kc + hi) * 16);
}
static __device__ __forceinline__ void ld_wf2(uint4* buf, const unsigned char* __restrict__ W2i,
                                              int kt2b, int l31, int hi) {
    #pragma unroll
    for (int d = 0; d < 2; ++d)
        #pragma unroll
        for (int n2 = 0; n2 < 4; ++n2)
            buf[d * 4 + n2] = *(const uint4*)(W2i + (n2 * 32 + l31) * 256
                                               + (2 * (kt2b + d) + hi) * 16);
}
static __device__ __forceinline__ void do_gt(const uint4* a1, int gt, const uint4* xb,
                                             uint4* pa, const unsigned char* smem,
                                             int e, int hi, float alph, float ce) {
    f32x16 h0 = {}, h1 = {};
    #pragma unroll
    for (int kc = 0; kc < 4; ++kc) {
        h0 = __builtin_amdgcn_mfma_f32_32x32x16_bf16(
                __builtin_bit_cast(bf16x8, a1[2 * kc]),
                __builtin_bit_cast(bf16x8, xb[2 * kc]), h0, 0, 0, 0);
        h1 = __builtin_amdgcn_mfma_f32_32x32x16_bf16(
                __builtin_bit_cast(bf16x8, a1[2 * kc + 1]),
                __builtin_bit_cast(bf16x8, xb[2 * kc + 1]), h1, 0, 0, 0);
    }
    #pragma unroll
    for (int q = 0; q < 4; ++q) {
        const int kt2 = 2 * gt + (q >> 1), half = q & 1;
        const int obase = kt2 * 16 + hi * 8 + half * 4;
        const f32x4 b1v = *(const f32x4*)(smem + B1_OFF + e * 512 + obase * 4);
        float hv[4];
        #pragma unroll
        for (int i = 0; i < 4; ++i) {
            float z = h0[q * 4 + i] + h1[q * 4 + i] + b1v[i];
            z = fmaxf(z, 0.f) + alph * fminf(z, 0.f);
            hv[i] = z * ce;
        }
        ((unsigned*)&pa[kt2])[half * 2]     = pk2(hv[0], hv[1]);
        ((unsigned*)&pa[kt2])[half * 2 + 1] = pk2(hv[2], hv[3]);
    }
}
static __device__ __forceinline__ void do_w2(const uint4* wf, int kt2b,
                                             const uint4* pa, f32x16* D) {
    #pragma unroll
    for (int d = 0; d < 2; ++d)
        #pragma unroll
        for (int n2 = 0; n2 < 4; ++n2)
            D[n2] = __builtin_amdgcn_mfma_f32_32x32x16_bf16(
                    __builtin_bit_cast(bf16x8, wf[d * 4 + n2]),
                    __builtin_bit_cast(bf16x8, pa[kt2b + d]), D[n2], 0, 0, 0);
}

// One compacted 32-slot group (one expert). Manual 1-stage-ahead pipeline:
// {issue 8 loads for k+1} SB {8 MFMAs on k} SB ... Two named buffers only
// (+60 regs max over R10) -> bounded liveness (R11's full unroll hoisted all
// loads -> spill); sched_barrier(0) fences stop both sinking and hoisting.
template<bool ADD>
static __device__ __forceinline__ void group_body(
        unsigned char* smem, const unsigned char* __restrict__ wimg,
        int g, int l31, int hi)
{
    const unsigned desc = ((const unsigned*)(smem + DSC_OFF))[g];
    const int e  = (int)(desc >> 16);
    const int s  = (int)(desc & 0xFFFFu) + l31;
    const unsigned tokRaw = ((const unsigned short*)(smem + SLT_OFF))[s];
    const float ce = ((const float*)(smem + SLC_OFF))[s];
    const int tokx  = (int)(tokRaw & 255u);
    const int rowOA = (tokRaw > 255u) ? 256 : (int)tokRaw;
    const float alph = ((const float*)(smem + AL_OFF))[e];

    const unsigned char* W1i = wimg + e * 32768;
    const unsigned char* W2i = wimg + 262144 + e * 32768;

    uint4 bufA[8], bufB[8], xb[8], pa[8];

    ld_a1(bufA, W1i, 0, l31, hi);          // first batch in flight under xb gather
    #pragma unroll
    for (int kc = 0; kc < 8; ++kc)
        xb[kc] = *(const uint4*)(smem + XT_OFF + tokx * 256
                                  + (((2 * kc + hi) ^ (tokx & 15)) * 16));
    SB();
    ld_a1(bufB, W1i, 1, l31, hi);  SB();
    do_gt(bufA, 0, xb, pa, smem, e, hi, alph, ce);  SB();
    ld_a1(bufA, W1i, 2, l31, hi);  SB();
    do_gt(bufB, 1, xb, pa, smem, e, hi, alph, ce);  SB();
    ld_a1(bufB, W1i, 3, l31, hi);  SB();
    do_gt(bufA, 2, xb, pa, smem, e, hi, alph, ce);  SB();
    ld_wf2(bufA, W2i, 0, l31, hi); SB();   // reuse bufA for W2 frags
    do_gt(bufB, 3, xb, pa, smem, e, hi, alph, ce);  SB();
    ld_wf2(bufB, W2i, 2, l31, hi); SB();

    f32x16 D[4] = {};   // D[n2]: rows p = n2*32+8q+4hi+i, col = this slot's token
    do_w2(bufA, 0, pa, D);         SB();
    ld_wf2(bufA, W2i, 4, l31, hi); SB();
    do_w2(bufB, 2, pa, D);         SB();
    ld_wf2(bufB, W2i, 6, l31, hi); SB();
    do_w2(bufA, 4, pa, D);         SB();
    do_w2(bufB, 6, pa, D);

    // + ce*b2, commit to OA (P0: write; P1: read-add-write)
    unsigned char* oarow = smem + OA_OFF + rowOA * OA_ROWB;
    #pragma unroll
    for (int n2 = 0; n2 < 4; ++n2) {
        #pragma unroll
        for (int q = 0; q < 4; ++q) {
            const int p0 = n2 * 32 + q * 8 + hi * 4;
            const f32x4 b2v = *(const f32x4*)(smem + B2_OFF + e * 512 + p0 * 4);
            float vv[4];
            #pragma unroll
            for (int i = 0; i < 4; ++i) vv[i] = D[n2][q * 4 + i] + ce * b2v[i];
            uint2* dst = (uint2*)(oarow + p0 * 2);
            if (ADD) {
                const uint2 old = *dst;
                vv[0] += ub((unsigned short)(old.x & 0xFFFFu));
                vv[1] += ub((unsigned short)(old.x >> 16));
                vv[2] += ub((unsigned short)(old.y & 0xFFFFu));
                vv[3] += ub((unsigned short)(old.y >> 16));
            }
            uint2 nw; nw.x = pk2(vv[0], vv[1]); nw.y = pk2(vv[2], vv[3]);
            *dst = nw;
        }
    }
}

__global__ __launch_bounds__(512) __attribute__((amdgpu_waves_per_eu(2, 2)))
void moe_main(const float* __restrict__ x,  const float* __restrict__ gw,
              const float* __restrict__ gb, const float* __restrict__ b1,
              const float* __restrict__ alpha, const float* __restrict__ b2,
              const unsigned char* __restrict__ wimg, float* __restrict__ out)
{
    __shared__ __align__(16) unsigned char smem[LDS_BYTES];
    const int t = threadIdx.x, lane = t & 63, w = t >> 6, blk = blockIdx.x;
    const int l31 = lane & 31, hi = lane >> 5;
    const size_t xbase = (size_t)(blk >> 8) * (size_t)(CH * SPAT) + (size_t)((blk & 255) << 8);
    const int m = w * 32 + l31;           // owner token (hi duplicates)
    unsigned* C = (unsigned*)(smem + CNT_OFF);

    if (t < 48) C[t] = 0;
    if (t < 256)      ((f32x4*)(smem + B1_OFF))[t]       = ((const f32x4*)b1)[t];
    else              ((f32x4*)(smem + B2_OFF))[t - 256] = ((const f32x4*)b2)[t - 256];
    if (t < 8) ((float*)(smem + AL_OFF))[t] = alpha[t];

    // ---- x load -> XT (bf16, swizzled) + fp32 gating ----
    f32x4 plo = {0.f,0.f,0.f,0.f}, phi = {0.f,0.f,0.f,0.f};
    #pragma unroll
    for (int kc = 0; kc < 8; ++kc) {
        const int c0 = kc * 16 + hi * 8;
        float v8[8];
        #pragma unroll
        for (int j = 0; j < 8; ++j) v8[j] = x[xbase + (size_t)(c0 + j) * SPAT + m];
        #pragma unroll
        for (int j = 0; j < 8; ++j) {
            const f32x4 g0 = *(const f32x4*)(gw + (c0 + j) * NE);
            const f32x4 g1 = *(const f32x4*)(gw + (c0 + j) * NE + 4);
            plo += v8[j] * g0; phi += v8[j] * g1;
        }
        uint4 pkv;
        pkv.x = pk2(v8[0], v8[1]); pkv.y = pk2(v8[2], v8[3]);
        pkv.z = pk2(v8[4], v8[5]); pkv.w = pk2(v8[6], v8[7]);
        *(uint4*)(smem + XT_OFF + m * 256 + (((2 * kc + hi) ^ (m & 15)) * 16)) = pkv;
    }
    #pragma unroll
    for (int i2 = 0; i2 < 4; ++i2) {
        plo[i2] += __shfl_xor(plo[i2], 32, 64);
        phi[i2] += __shfl_xor(phi[i2], 32, 64);
    }
    int i0, i1; float q0, q1;
    {
        float lg[8];
        #pragma unroll
        for (int e2 = 0; e2 < 4; ++e2) { lg[e2] = plo[e2] + gb[e2]; lg[4 + e2] = phi[e2] + gb[4 + e2]; }
        i0 = 0; float v0 = lg[0];
        #pragma unroll
        for (int e2 = 1; e2 < 8; ++e2) if (lg[e2] > v0) { v0 = lg[e2]; i0 = e2; }
        i1 = -1; float v1 = -3.4e38f;
        #pragma unroll
        for (int e2 = 0; e2 < 8; ++e2) if (e2 != i0 && lg[e2] > v1) { v1 = lg[e2]; i1 = e2; }
        const float d = expf(v1 - v0);
        q0 = 1.f / (1.f + d);
        q1 = d   / (1.f + d);
    }
    __syncthreads();   // S1

    if (hi == 0) {
        atomicAdd(&C[i0], 1u);
        atomicAdd(&C[8 + i1], 1u);
    }
    __syncthreads();   // S2

    if (t == 0) {      // build bases, cursors, group descriptors (expert-sorted)
        unsigned* dsc = (unsigned*)(smem + DSC_OFF);
        int ng = 0; unsigned base = 0;
        for (int e = 0; e < 8; ++e) {
            const unsigned c = C[e], gc = (c + 31) >> 5;
            C[16 + e] = base; C[32 + e] = base;
            for (unsigned k = 0; k < gc; ++k) dsc[ng++] = ((unsigned)e << 16) | (base + k * 32);
            base += gc * 32;
        }
        ((int*)(smem + NG_OFF))[0] = ng;
        for (int e = 0; e < 8; ++e) {
            const unsigned c = C[8 + e], gc = (c + 31) >> 5;
            C[24 + e] = base; C[40 + e] = base;
            for (unsigned k = 0; k < gc; ++k) dsc[ng++] = ((unsigned)e << 16) | (base + k * 32);
            base += gc * 32;
        }
        ((int*)(smem + NG_OFF))[1] = ng;
    }
    __syncthreads();   // S3

    if (hi == 0) {     // scatter
        const unsigned pP = atomicAdd(&C[16 + i0], 1u);
        ((unsigned short*)(smem + SLT_OFF))[pP] = (unsigned short)m;
        ((float*)(smem + SLC_OFF))[pP] = q0;
        const unsigned pQ = atomicAdd(&C[24 + i1], 1u);
        ((unsigned short*)(smem + SLT_OFF))[pQ] = (unsigned short)m;
        ((float*)(smem + SLC_OFF))[pQ] = q1;
    }
    __syncthreads();   // S4

    if (t < 16) {      // pad each expert segment to x32 with dummy slots
        const int e = t & 7;
        const unsigned c  = (t < 8) ? C[e] : C[8 + e];
        const unsigned bs = (t < 8) ? C[32 + e] : C[40 + e];
        const unsigned en = bs + ((c + 31) & ~31u);
        for (unsigned s2 = bs + c; s2 < en; ++s2) {
            ((unsigned short*)(smem + SLT_OFF))[s2] = 0xFFFFu;
            ((float*)(smem + SLC_OFF))[s2] = 0.f;
        }
    }
    __syncthreads();   // S5

    const int NGP = ((const int*)(smem + NG_OFF))[0];
    const int NGT = ((const int*)(smem + NG_OFF))[1];

    // Phase P0: primary slots (every token exactly once) -> WRITE OA
    {
        const int g0 = (w * NGP) >> 3, g1 = ((w + 1) * NGP) >> 3;
        #pragma unroll 1
        for (int g = g0; g < g1; ++g) group_body<false>(smem, wimg, g, l31, hi);
    }
    __syncthreads();   // S6: OA fully initialized
    // Phase P1: secondary slots -> read-add-write OA
    {
        const int ns = NGT - NGP;
        const int g0 = NGP + ((w * ns) >> 3), g1 = NGP + (((w + 1) * ns) >> 3);
        #pragma unroll 1
        for (int g = g0; g < g1; ++g) group_body<true>(smem, wimg, g, l31, hi);
    }
    __syncthreads();   // S7

    // ---- epilogue: out[p][tok] = OA[tok][p] + x[p][tok] ----
    {
        const int etok = t & 255;
        const int gb8  = (t >> 8) * 8;
        const unsigned char* oarow = smem + OA_OFF + etok * OA_ROWB;
        #pragma unroll
        for (int gi = 0; gi < 8; ++gi) {
            const int gran = gb8 + gi;
            const uint4 r = *(const uint4*)(oarow + gran * 16);
            const unsigned short* u = (const unsigned short*)&r;
            #pragma unroll
            for (int j = 0; j < 8; ++j) {
                const int p = gran * 8 + j;
                const size_t a = xbase + (size_t)p * SPAT + etok;
                out[a] = ub(u[j]) + x[a];
            }
        }
    }
}

extern "C" void kernel_launch(void* const* d_in, const int* in_sizes, int n_in,
                              void* d_out, int out_size, void* d_ws, size_t ws_size,
                              hipStream_t stream) {
    const float* x  = (const float*)d_in[0];
    const float* gw = (const float*)d_in[1];
    const float* gb = (const float*)d_in[2];
    const float* W1 = (const float*)d_in[3];
    const float* b1 = (const float*)d_in[4];
    const float* al = (const float*)d_in[5];
    const float* W2 = (const float*)d_in[6];
    const float* b2 = (const float*)d_in[7];
    (void)in_sizes; (void)n_in; (void)out_size; (void)ws_size;
    unsigned char* wimg = (unsigned char*)d_ws;   // needs 512 KiB
    float* out = (float*)d_out;

    conv_w<<<dim3(128), dim3(256), 0, stream>>>(W1, W2, wimg);
    moe_main<<<dim3(512), dim3(512), 0, stream>>>(x, gw, gb, b1, al, b2, wimg, out);
}

// Round 13
// 127.258 us; speedup vs baseline: 1.2572x; 1.1060x over previous
//
#include <hip/hip_runtime.h>

typedef float f32x4  __attribute__((ext_vector_type(4)));
typedef float f32x16 __attribute__((ext_vector_type(16)));
typedef __bf16 bf16x8 __attribute__((ext_vector_type(8)));

#define SPAT 65536   // t*h*w
#define CH   128
#define NE   8

// LDS layout (bytes): 4 x 32KB weight ring + params
#define SLOT(i)  ((i) * 32768)
#define B1_OFF   131072   // 4096 : b1 f32[8][128]
#define B2T_OFF  135168   // 4096 : b2^T bf16[128][16] (e 8..15 zero)
#define AL_OFF   139264   // 32   : alpha f32[8]
#define LDS_BYTES 139296

static __device__ __forceinline__ unsigned short f2b(float f) {
    unsigned u = __builtin_bit_cast(unsigned, f);
    unsigned r = u + 0x7FFFu + ((u >> 16) & 1u);
    return (unsigned short)(r >> 16);
}
static __device__ __forceinline__ unsigned pk2(float a, float b) {
    return (unsigned)f2b(a) | ((unsigned)f2b(b) << 16);
}

typedef const __attribute__((address_space(1))) void* as1cp;
typedef __attribute__((address_space(3))) void* as3p;
static __device__ __forceinline__ void gload16(const void* g, void* l) {
    __builtin_amdgcn_global_load_lds((as1cp)g, (as3p)l, 16, 0, 0);
}

// Pre-convert W1/W2 fp32 -> bf16 images for 32x32x16 MFMA (verified R7/R8):
//  - 16B-granule XOR swizzle within each 256B row: stored[p] = src granule (p ^ (r&15))
//  - W1 rows PERMUTED so GEMM1's D-fragment == GEMM2's A-fragment:
//      image row r holds real W1 row P(r): n = 4*(r>>5) + ((r>>3)&3),
//      P(r) = (n>>1)*16 + ((r>>2)&1)*8 + (n&1)*4 + (r&3).
//  - W2 rows natural.
__global__ void conv_w(const float* __restrict__ W1, const float* __restrict__ W2,
                       unsigned char* __restrict__ wimg) {
    const int gid = blockIdx.x * 256 + threadIdx.x;   // 32768 granules
    const int mat = gid >> 14;
    const int e   = (gid >> 11) & 7;
    const int r   = (gid >> 4) & 127;
    const int p   = gid & 15;
    const int sg  = p ^ (r & 15);
    int src_row = r;
    if (mat == 0) {
        const int n = 4 * (r >> 5) + ((r >> 3) & 3);
        src_row = (n >> 1) * 16 + ((r >> 2) & 1) * 8 + (n & 1) * 4 + (r & 3);
    }
    const float* s = (mat ? W2 : W1) + (e * 16384 + src_row * 128 + sg * 8);
    uint4 pk;
    pk.x = pk2(s[0], s[1]); pk.y = pk2(s[2], s[3]);
    pk.z = pk2(s[4], s[5]); pk.w = pk2(s[6], s[7]);
    *(uint4*)(wimg + mat * 262144 + e * 32768 + r * 256 + p * 16) = pk;
}

// stage one 32KB weight image into an LDS slot (4 x gload16 per thread, 512 thr)
static __device__ __forceinline__ void stage_w(const unsigned char* __restrict__ src,
                                               unsigned char* dst, int t) {
    const int off = t * 16;
    gload16(src + off,          dst + off);
    gload16(src + 8192  + off,  dst + 8192  + off);
    gload16(src + 16384 + off,  dst + 16384 + off);
    gload16(src + 24576 + off,  dst + 24576 + off);
}

// ---- staggered inner-loop helpers (all indices compile-time) ----
static __device__ __forceinline__ void ld_a1(uint4* buf, const unsigned char* smem,
                                             unsigned waOff, int g, int ltok, int hi, int l15) {
    #pragma unroll
    for (int kc = 0; kc < 8; ++kc)
        buf[kc] = *(const uint4*)(smem + waOff + (g * 32 + ltok) * 256
                                   + (((kc * 2 + hi) ^ l15) * 16));
}
static __device__ __forceinline__ void body(const uint4* a1, int g, const uint4* xb,
        const unsigned char* smem, unsigned wbOff, int e, int ltok, int hi, int l15,
        float alph, float ce, f32x16* acc) {
    // two independent MFMA chains (R8 had one 8-deep dependent chain)
    f32x16 h0 = {}, h1 = {};
    #pragma unroll
    for (int kc = 0; kc < 4; ++kc) {
        h0 = __builtin_amdgcn_mfma_f32_32x32x16_bf16(
                __builtin_bit_cast(bf16x8, a1[2 * kc]),
                __builtin_bit_cast(bf16x8, xb[2 * kc]), h0, 0, 0, 0);
        h1 = __builtin_amdgcn_mfma_f32_32x32x16_bf16(
                __builtin_bit_cast(bf16x8, a1[2 * kc + 1]),
                __builtin_bit_cast(bf16x8, xb[2 * kc + 1]), h1, 0, 0, 0);
    }
    uint4 pa2[2];
    #pragma unroll
    for (int q = 0; q < 4; ++q) {
        const int n = 4 * g + q, kt2 = n >> 1, half = n & 1;
        const int obase = kt2 * 16 + hi * 8 + half * 4;
        const f32x4 b1v = *(const f32x4*)(smem + B1_OFF + e * 512 + obase * 4);
        float hv[4];
        #pragma unroll
        for (int i = 0; i < 4; ++i) {
            float z = h0[q * 4 + i] + h1[q * 4 + i] + b1v[i];
            z = (z > 0.f) ? z : alph * z;
            hv[i] = z * ce;
        }
        ((unsigned*)&pa2[q >> 1])[half * 2]     = pk2(hv[0], hv[1]);
        ((unsigned*)&pa2[q >> 1])[half * 2 + 1] = pk2(hv[2], hv[3]);
    }
    #pragma unroll
    for (int dk = 0; dk < 2; ++dk) {
        const int kt2 = 2 * g + dk;
        #pragma unroll
        for (int n2 = 0; n2 < 4; ++n2) {
            const uint4 wf = *(const uint4*)(smem + wbOff + (n2 * 32 + ltok) * 256
                                  + (((kt2 * 2 + hi) ^ l15) * 16));
            acc[n2] = __builtin_amdgcn_mfma_f32_32x32x16_bf16(
                    __builtin_bit_cast(bf16x8, pa2[dk]),
                    __builtin_bit_cast(bf16x8, wf), acc[n2], 0, 0, 0);
        }
    }
}

// Occupancy: (2,2) pin -> 256-reg budget, no spill (R8 law). Working set
// ~200 regs incl. the second a1 buffer for the 1-group-ahead stagger.
__global__ __launch_bounds__(512) __attribute__((amdgpu_waves_per_eu(2, 2)))
void moe_main(const float* __restrict__ x,  const float* __restrict__ gw,
              const float* __restrict__ gb, const float* __restrict__ b1,
              const float* __restrict__ alpha, const float* __restrict__ b2,
              const unsigned char* __restrict__ wimg, float* __restrict__ out)
{
    __shared__ __align__(16) unsigned char smem[LDS_BYTES];
    const int t = threadIdx.x, lane = t & 63, w = t >> 6, blk = blockIdx.x;
    const int ltok = lane & 31, hi = lane >> 5, l15 = lane & 15;
    const size_t xbase = (size_t)(blk >> 8) * (size_t)(CH * SPAT) + (size_t)((blk & 255) << 8);
    const int m = w * 32 + ltok;            // this lane's block-local token

    // W1[0]->slot0, W2[0]->slot1: issue at entry, land by S1
    stage_w(wimg,          smem + SLOT(0), t);
    stage_w(wimg + 262144, smem + SLOT(1), t);

    // stage small params
    if (t < 256) ((f32x4*)(smem + B1_OFF))[t] = ((const f32x4*)b1)[t];
    if (t < 128) {
        uint4 pkv, z4 = {0u, 0u, 0u, 0u};
        pkv.x = pk2(b2[0 * 128 + t], b2[1 * 128 + t]);
        pkv.y = pk2(b2[2 * 128 + t], b2[3 * 128 + t]);
        pkv.z = pk2(b2[4 * 128 + t], b2[5 * 128 + t]);
        pkv.w = pk2(b2[6 * 128 + t], b2[7 * 128 + t]);
        *(uint4*)(smem + B2T_OFF + t * 32)      = pkv;
        *(uint4*)(smem + B2T_OFF + t * 32 + 16) = z4;
    } else if (t >= 128 && t < 136) {
        ((float*)(smem + AL_OFF))[t - 128] = alpha[t - 128];
    }

    // ---- per-kc: load x(8ch), fp32 gating partials (gw from global/L2), pack xb ----
    f32x4 plo = {0.f,0.f,0.f,0.f}, phi = {0.f,0.f,0.f,0.f};
    uint4 xb[8];
    #pragma unroll
    for (int kc = 0; kc < 8; ++kc) {
        const int c0 = kc * 16 + hi * 8;
        float v8[8];
        #pragma unroll
        for (int j = 0; j < 8; ++j) v8[j] = x[xbase + (size_t)(c0 + j) * SPAT + m];
        #pragma unroll
        for (int j = 0; j < 8; ++j) {
            const f32x4 g0 = *(const f32x4*)(gw + (c0 + j) * NE);
            const f32x4 g1 = *(const f32x4*)(gw + (c0 + j) * NE + 4);
            plo += v8[j] * g0; phi += v8[j] * g1;
        }
        xb[kc].x = pk2(v8[0], v8[1]); xb[kc].y = pk2(v8[2], v8[3]);
        xb[kc].z = pk2(v8[4], v8[5]); xb[kc].w = pk2(v8[6], v8[7]);
    }
    #pragma unroll
    for (int i2 = 0; i2 < 4; ++i2) {
        plo[i2] += __shfl_xor(plo[i2], 32, 64);
        phi[i2] += __shfl_xor(phi[i2], 32, 64);
    }
    int i0, i1; float q0, q1; uint4 cbw;
    {
        float lg[8];
        #pragma unroll
        for (int e2 = 0; e2 < 4; ++e2) { lg[e2] = plo[e2] + gb[e2]; lg[4 + e2] = phi[e2] + gb[4 + e2]; }
        i0 = 0; float v0 = lg[0];
        #pragma unroll
        for (int e2 = 1; e2 < 8; ++e2) if (lg[e2] > v0) { v0 = lg[e2]; i0 = e2; }
        i1 = -1; float v1 = -3.4e38f;
        #pragma unroll
        for (int e2 = 0; e2 < 8; ++e2) if (e2 != i0 && lg[e2] > v1) { v1 = lg[e2]; i1 = e2; }
        const float d = expf(v1 - v0);
        q0 = 1.f / (1.f + d);
        q1 = d   / (1.f + d);
        float cb[8];
        #pragma unroll
        for (int e2 = 0; e2 < 8; ++e2) cb[e2] = (e2 == i0) ? q0 : ((e2 == i1) ? q1 : 0.f);
        cbw.x = pk2(cb[0], cb[1]); cbw.y = pk2(cb[2], cb[3]);
        cbw.z = pk2(cb[4], cb[5]); cbw.w = pk2(cb[6], cb[7]);
    }
    __syncthreads();   // S1: W1[0]/W2[0] landed; b1/b2T/alpha visible

    f32x16 acc[4] = {};   // acc[n2]: D[tok 32][p = n2*32 + ltok]

    #pragma unroll 1
    for (int e = 0; e < NE; ++e) {
        const int cur = (e & 1) << 1;   // slots: even e -> 0,1 ; odd e -> 2,3
        if (e < 7) {                    // prefetch next pair into the other slots
            stage_w(wimg + (e + 1) * 32768,          smem + SLOT(cur ^ 2), t);
            stage_w(wimg + 262144 + (e + 1) * 32768, smem + SLOT((cur ^ 2) + 1), t);
        }
        const unsigned waOff = (unsigned)SLOT(cur);
        const unsigned wbOff = (unsigned)SLOT(cur) + 32768u;
        const float alph = ((const float*)(smem + AL_OFF))[e];
        const float ce = (i0 == e) ? q0 : ((i1 == e) ? q1 : 0.f);

        // 1-group-ahead stagger: issue a1 ds_reads for g+1 before g's compute.
        // Two named buffers -> bounded liveness (R11 lesson); no unroll-1
        // serialization (R10 lesson).
        uint4 bufA[8], bufB[8];
        ld_a1(bufA, smem, waOff, 0, ltok, hi, l15);
        ld_a1(bufB, smem, waOff, 1, ltok, hi, l15);
        body(bufA, 0, xb, smem, wbOff, e, ltok, hi, l15, alph, ce, acc);
        ld_a1(bufA, smem, waOff, 2, ltok, hi, l15);
        body(bufB, 1, xb, smem, wbOff, e, ltok, hi, l15, alph, ce, acc);
        ld_a1(bufB, smem, waOff, 3, ltok, hi, l15);
        body(bufA, 2, xb, smem, wbOff, e, ltok, hi, l15, alph, ce, acc);
        body(bufB, 3, xb, smem, wbOff, e, ltok, hi, l15, alph, ce, acc);

        __syncthreads();   // phase end: prefetch drained; cur slots free next iter
    }

    // ---- bias-combine as one K=16 MFMA per p-group: acc += combine . b2 ----
    {
        const uint4 z4 = {0u, 0u, 0u, 0u};
        const uint4 aop = hi ? z4 : cbw;
        #pragma unroll
        for (int n2 = 0; n2 < 4; ++n2) {
            const uint4 bop = *(const uint4*)(smem + B2T_OFF + (n2 * 32 + ltok) * 32 + hi * 16);
            acc[n2] = __builtin_amdgcn_mfma_f32_32x32x16_bf16(
                    __builtin_bit_cast(bf16x8, aop),
                    __builtin_bit_cast(bf16x8, bop), acc[n2], 0, 0, 0);
        }
    }

    // ---- epilogue: residual + f32x4 stores (D rows: tok = w*32 + 8q + 4hi + i) ----
    #pragma unroll
    for (int n2 = 0; n2 < 4; ++n2) {
        const int p = n2 * 32 + ltok;
        #pragma unroll
        for (int q = 0; q < 4; ++q) {
            const int tok0 = w * 32 + q * 8 + hi * 4;
            const size_t a = xbase + (size_t)p * SPAT + tok0;
            const f32x4 xv = *(const f32x4*)(x + a);
            f32x4 r;
            #pragma unroll
            for (int i = 0; i < 4; ++i) r[i] = acc[n2][q * 4 + i] + xv[i];
            *(f32x4*)(out + a) = r;
        }
    }
}

extern "C" void kernel_launch(void* const* d_in, const int* in_sizes, int n_in,
                              void* d_out, int out_size, void* d_ws, size_t ws_size,
                              hipStream_t stream) {
    const float* x  = (const float*)d_in[0];
    const float* gw = (const float*)d_in[1];
    const float* gb = (const float*)d_in[2];
    const float* W1 = (const float*)d_in[3];
    const float* b1 = (const float*)d_in[4];
    const float* al = (const float*)d_in[5];
    const float* W2 = (const float*)d_in[6];
    const float* b2 = (const float*)d_in[7];
    (void)in_sizes; (void)n_in; (void)out_size; (void)ws_size;
    unsigned char* wimg = (unsigned char*)d_ws;   // needs 512 KiB
    float* out = (float*)d_out;

    conv_w<<<dim3(128), dim3(256), 0, stream>>>(W1, W2, wimg);
    moe_main<<<dim3(512), dim3(512), 0, stream>>>(x, gw, gb, b1, al, b2, wimg, out);
}

// Round 14
// 122.145 us; speedup vs baseline: 1.3099x; 1.0419x over previous
//
#include <hip/hip_runtime.h>

typedef float f32x4  __attribute__((ext_vector_type(4)));
typedef float f32x16 __attribute__((ext_vector_type(16)));
typedef __bf16 bf16x8 __attribute__((ext_vector_type(8)));

#define SPAT 65536   // t*h*w
#define CH   128
#define NE   8

// LDS layout (bytes): 2 x 32KB W1 ring + params = 73.8 KB
#define SLOT(i)  ((i) * 32768)
#define B1_OFF   65536    // 4096 : b1 f32[8][128]
#define B2T_OFF  69632    // 4096 : b2^T bf16[128][16] (e 8..15 zero)
#define AL_OFF   73728    // 32   : alpha f32[8]
#define LDS_BYTES 73760

static __device__ __forceinline__ unsigned short bf(float f) {
    __bf16 h = (__bf16)f; return __builtin_bit_cast(unsigned short, h);
}
static __device__ __forceinline__ unsigned pk2(float a, float b) {
    return (unsigned)bf(a) | ((unsigned)bf(b) << 16);
}

typedef const __attribute__((address_space(1))) void* as1cp;
typedef __attribute__((address_space(3))) void* as3p;
static __device__ __forceinline__ void gload16(const void* g, void* l) {
    __builtin_amdgcn_global_load_lds((as1cp)g, (as3p)l, 16, 0, 0);
}

// Pre-convert W1/W2 fp32 -> bf16 images.
// W1 (LDS-staged): 16B-granule XOR swizzle per 256B row, rows PERMUTED so
//   GEMM1's D-fragment == GEMM2's A-fragment (R7/R8-verified):
//   image row r holds real W1 row P(r): n = 4*(r>>5)+((r>>3)&3),
//   P(r) = (n>>1)*16 + ((r>>2)&1)*8 + (n&1)*4 + (r&3).
// W2 (read straight from global/L1): LANE-LINEAR layout — instruction (kt2,n2)
//   reads one contiguous 1KB line: off = (kt2*4+n2)*1024 + lane*16, where
//   lane = hi*32+ltok maps to (row = n2*32+ltok, granule = 2*kt2+hi):
//   store granule p of row r at (( (p>>1)*4 + (r>>5) )<<10) + ((p&1)<<9) + (r&31)*16.
__global__ void conv_w(const float* __restrict__ W1, const float* __restrict__ W2,
                       unsigned char* __restrict__ wimg) {
    const int gid = blockIdx.x * 256 + threadIdx.x;   // 32768 granules
    const int mat = gid >> 14;
    const int e   = (gid >> 11) & 7;
    const int r   = (gid >> 4) & 127;
    const int p   = gid & 15;
    if (mat == 0) {
        const int sg = p ^ (r & 15);
        const int n = 4 * (r >> 5) + ((r >> 3) & 3);
        const int src_row = (n >> 1) * 16 + ((r >> 2) & 1) * 8 + (n & 1) * 4 + (r & 3);
        const float* s = W1 + (e * 16384 + src_row * 128 + sg * 8);
        uint4 pk;
        pk.x = pk2(s[0], s[1]); pk.y = pk2(s[2], s[3]);
        pk.z = pk2(s[4], s[5]); pk.w = pk2(s[6], s[7]);
        *(uint4*)(wimg + e * 32768 + r * 256 + p * 16) = pk;
    } else {
        const float* s = W2 + (e * 16384 + r * 128 + p * 8);
        uint4 pk;
        pk.x = pk2(s[0], s[1]); pk.y = pk2(s[2], s[3]);
        pk.z = pk2(s[4], s[5]); pk.w = pk2(s[6], s[7]);
        *(uint4*)(wimg + 262144 + e * 32768
                  + ((((p >> 1) * 4 + (r >> 5)) << 10) + ((p & 1) << 9) + (r & 31) * 16)) = pk;
    }
}

// stage one 32KB W1 image into an LDS slot (4 x gload16 per thread, 512 thr)
static __device__ __forceinline__ void stage_w32(const unsigned char* __restrict__ src,
                                                 unsigned char* dst, int t) {
    const int off = t * 16;
    gload16(src + off,          dst + off);
    gload16(src + 8192  + off,  dst + 8192  + off);
    gload16(src + 16384 + off,  dst + 16384 + off);
    gload16(src + 24576 + off,  dst + 24576 + off);
}

// (2,2) pin -> 256-reg budget, no spill (R8 law; working set ~190 incl AGPRs).
__global__ __launch_bounds__(512) __attribute__((amdgpu_waves_per_eu(2, 2)))
void moe_main(const float* __restrict__ x,  const float* __restrict__ gw,
              const float* __restrict__ gb, const float* __restrict__ b1,
              const float* __restrict__ alpha, const float* __restrict__ b2,
              const unsigned char* __restrict__ wimg, float* __restrict__ out)
{
    __shared__ __align__(16) unsigned char smem[LDS_BYTES];
    const int t = threadIdx.x, lane = t & 63, w = t >> 6, blk = blockIdx.x;
    const int ltok = lane & 31, hi = lane >> 5, l15 = lane & 15;
    const size_t xbase = (size_t)(blk >> 8) * (size_t)(CH * SPAT) + (size_t)((blk & 255) << 8);
    const int m = w * 32 + ltok;            // this lane's block-local token
    const int wlane = (hi << 9) + ltok * 16; // per-lane byte offset in W2 lines

    // W1[0] -> slot0: issue at entry, lands by S1
    stage_w32(wimg, smem + SLOT(0), t);

    // stage small params
    if (t < 256) ((f32x4*)(smem + B1_OFF))[t] = ((const f32x4*)b1)[t];
    if (t < 128) {
        uint4 pkv, z4 = {0u, 0u, 0u, 0u};
        pkv.x = pk2(b2[0 * 128 + t], b2[1 * 128 + t]);
        pkv.y = pk2(b2[2 * 128 + t], b2[3 * 128 + t]);
        pkv.z = pk2(b2[4 * 128 + t], b2[5 * 128 + t]);
        pkv.w = pk2(b2[6 * 128 + t], b2[7 * 128 + t]);
        *(uint4*)(smem + B2T_OFF + t * 32)      = pkv;
        *(uint4*)(smem + B2T_OFF + t * 32 + 16) = z4;
    } else if (t >= 128 && t < 136) {
        ((float*)(smem + AL_OFF))[t - 128] = alpha[t - 128];
    }

    // ---- per-kc: load x(8ch), fp32 gating partials (gw from global/L2), pack xb ----
    f32x4 plo = {0.f,0.f,0.f,0.f}, phi = {0.f,0.f,0.f,0.f};
    uint4 xb[8];
    #pragma unroll
    for (int kc = 0; kc < 8; ++kc) {
        const int c0 = kc * 16 + hi * 8;
        float v8[8];
        #pragma unroll
        for (int j = 0; j < 8; ++j) v8[j] = x[xbase + (size_t)(c0 + j) * SPAT + m];
        #pragma unroll
        for (int j = 0; j < 8; ++j) {
            const f32x4 g0 = *(const f32x4*)(gw + (c0 + j) * NE);
            const f32x4 g1 = *(const f32x4*)(gw + (c0 + j) * NE + 4);
            plo += v8[j] * g0; phi += v8[j] * g1;
        }
        xb[kc].x = pk2(v8[0], v8[1]); xb[kc].y = pk2(v8[2], v8[3]);
        xb[kc].z = pk2(v8[4], v8[5]); xb[kc].w = pk2(v8[6], v8[7]);
    }
    #pragma unroll
    for (int i2 = 0; i2 < 4; ++i2) {
        plo[i2] += __shfl_xor(plo[i2], 32, 64);
        phi[i2] += __shfl_xor(phi[i2], 32, 64);
    }
    int i0, i1; float q0, q1; uint4 cbw;
    {
        float lg[8];
        #pragma unroll
        for (int e2 = 0; e2 < 4; ++e2) { lg[e2] = plo[e2] + gb[e2]; lg[4 + e2] = phi[e2] + gb[4 + e2]; }
        i0 = 0; float v0 = lg[0];
        #pragma unroll
        for (int e2 = 1; e2 < 8; ++e2) if (lg[e2] > v0) { v0 = lg[e2]; i0 = e2; }
        i1 = -1; float v1 = -3.4e38f;
        #pragma unroll
        for (int e2 = 0; e2 < 8; ++e2) if (e2 != i0 && lg[e2] > v1) { v1 = lg[e2]; i1 = e2; }
        const float d = expf(v1 - v0);
        q0 = 1.f / (1.f + d);
        q1 = d   / (1.f + d);
        float cb[8];
        #pragma unroll
        for (int e2 = 0; e2 < 8; ++e2) cb[e2] = (e2 == i0) ? q0 : ((e2 == i1) ? q1 : 0.f);
        cbw.x = pk2(cb[0], cb[1]); cbw.y = pk2(cb[2], cb[3]);
        cbw.z = pk2(cb[4], cb[5]); cbw.w = pk2(cb[6], cb[7]);
    }
    __syncthreads();   // S1: W1[0] landed; params visible

    f32x16 acc[4] = {};   // acc[n2]: D[tok 32][p = n2*32 + ltok]

    #pragma unroll 1
    for (int e = 0; e < NE; ++e) {
        const int cur = e & 1;
        if (e < 7) stage_w32(wimg + (e + 1) * 32768, smem + SLOT(cur ^ 1), t);
        const unsigned char* WA  = smem + SLOT(cur);
        const unsigned char* W2g = wimg + 262144 + e * 32768;   // global, L1-resident
        const float alph = ((const float*)(smem + AL_OFF))[e];
        const float ce = (i0 == e) ? q0 : ((i1 == e) ? q1 : 0.f);

        // fused per-32-row group: GEMM1 (a1 from LDS) -> pa -> GEMM2 (wf from L1)
        #pragma unroll 1
        for (int g = 0; g < 4; ++g) {
            uint4 a1[8];
            #pragma unroll
            for (int kc = 0; kc < 8; ++kc)
                a1[kc] = *(const uint4*)(WA + (g * 32 + ltok) * 256
                                          + (((kc * 2 + hi) ^ l15) * 16));
            f32x16 h0 = {}, h1 = {};
            #pragma unroll
            for (int kc = 0; kc < 4; ++kc) {
                h0 = __builtin_amdgcn_mfma_f32_32x32x16_bf16(
                        __builtin_bit_cast(bf16x8, a1[2 * kc]),
                        __builtin_bit_cast(bf16x8, xb[2 * kc]), h0, 0, 0, 0);
                h1 = __builtin_amdgcn_mfma_f32_32x32x16_bf16(
                        __builtin_bit_cast(bf16x8, a1[2 * kc + 1]),
                        __builtin_bit_cast(bf16x8, xb[2 * kc + 1]), h1, 0, 0, 0);
            }
            uint4 pa2[2];
            #pragma unroll
            for (int q = 0; q < 4; ++q) {
                const int n = 4 * g + q, kt2 = n >> 1, half = n & 1;
                const int obase = kt2 * 16 + hi * 8 + half * 4;
                const f32x4 b1v = *(const f32x4*)(smem + B1_OFF + e * 512 + obase * 4);
                float hv[4];
                #pragma unroll
                for (int i = 0; i < 4; ++i) {
                    float z = h0[q * 4 + i] + h1[q * 4 + i] + b1v[i];
                    z = (z > 0.f) ? z : alph * z;
                    hv[i] = z * ce;
                }
                ((unsigned*)&pa2[q >> 1])[half * 2]     = pk2(hv[0], hv[1]);
                ((unsigned*)&pa2[q >> 1])[half * 2 + 1] = pk2(hv[2], hv[3]);
            }
            #pragma unroll
            for (int dk = 0; dk < 2; ++dk) {
                const int kt2 = 2 * g + dk;
                #pragma unroll
                for (int n2 = 0; n2 < 4; ++n2) {
                    const uint4 wf = *(const uint4*)(W2g + ((kt2 * 4 + n2) << 10) + wlane);
                    acc[n2] = __builtin_amdgcn_mfma_f32_32x32x16_bf16(
                            __builtin_bit_cast(bf16x8, pa2[dk]),
                            __builtin_bit_cast(bf16x8, wf), acc[n2], 0, 0, 0);
                }
            }
        }
        __syncthreads();   // phase end: W1 prefetch drained; cur slot free next iter
    }

    // ---- bias-combine as one K=16 MFMA per p-group: acc += combine . b2 ----
    {
        const uint4 z4 = {0u, 0u, 0u, 0u};
        const uint4 aop = hi ? z4 : cbw;
        #pragma unroll
        for (int n2 = 0; n2 < 4; ++n2) {
            const uint4 bop = *(const uint4*)(smem + B2T_OFF + (n2 * 32 + ltok) * 32 + hi * 16);
            acc[n2] = __builtin_amdgcn_mfma_f32_32x32x16_bf16(
                    __builtin_bit_cast(bf16x8, aop),
                    __builtin_bit_cast(bf16x8, bop), acc[n2], 0, 0, 0);
        }
    }

    // ---- epilogue: residual + f32x4 stores (D rows: tok = w*32 + 8q + 4hi + i) ----
    #pragma unroll
    for (int n2 = 0; n2 < 4; ++n2) {
        const int p = n2 * 32 + ltok;
        #pragma unroll
        for (int q = 0; q < 4; ++q) {
            const int tok0 = w * 32 + q * 8 + hi * 4;
            const size_t a = xbase + (size_t)p * SPAT + tok0;
            const f32x4 xv = *(const f32x4*)(x + a);
            f32x4 r;
            #pragma unroll
            for (int i = 0; i < 4; ++i) r[i] = acc[n2][q * 4 + i] + xv[i];
            *(f32x4*)(out + a) = r;
        }
    }
}

extern "C" void kernel_launch(void* const* d_in, const int* in_sizes, int n_in,
                              void* d_out, int out_size, void* d_ws, size_t ws_size,
                              hipStream_t stream) {
    const float* x  = (const float*)d_in[0];
    const float* gw = (const float*)d_in[1];
    const float* gb = (const float*)d_in[2];
    const float* W1 = (const float*)d_in[3];
    const float* b1 = (const float*)d_in[4];
    const float* al = (const float*)d_in[5];
    const float* W2 = (const float*)d_in[6];
    const float* b2 = (const float*)d_in[7];
    (void)in_sizes; (void)n_in; (void)out_size; (void)ws_size;
    unsigned char* wimg = (unsigned char*)d_ws;   // needs 512 KiB
    float* out = (float*)d_out;

    conv_w<<<dim3(128), dim3(256), 0, stream>>>(W1, W2, wimg);
    moe_main<<<dim3(512), dim3(512), 0, stream>>>(x, gw, gb, b1, al, b2, wimg, out);
}